// Round 2
// baseline (296.413 us; speedup 1.0000x reference)
//
#include <hip/hip_runtime.h>

#define DT 0.001f

typedef float f4 __attribute__((ext_vector_type(4)));

// DPP row_ror ring all-reduce within each aligned group of 16 lanes.
// row_ror:n = dpp_ctrl 0x120|n, confined to rows of 16 — exactly our groups.
template<int CTRL>
__device__ __forceinline__ float dpp_add(float v) {
    int r = __builtin_amdgcn_update_dpp(0, __float_as_int(v), CTRL, 0xf, 0xf, false);
    return v + __int_as_float(r);
}

__device__ __forceinline__ float reduce16(float t) {
    t = dpp_add<0x121>(t);  // row_ror:1
    t = dpp_add<0x122>(t);  // row_ror:2
    t = dpp_add<0x124>(t);  // row_ror:4
    t = dpp_add<0x128>(t);  // row_ror:8  -> full 16-lane sum in every lane
    return t;
}

__global__ __launch_bounds__(256) void nh_kernel(
    const float* __restrict__ x0, const float* __restrict__ v0,
    const float* __restrict__ alpha0,
    const float* __restrict__ kT_p, const float* __restrict__ mass_p,
    const float* __restrict__ Q_p,
    const int* __restrict__ n_steps_p, const int* __restrict__ store_every_p,
    float* __restrict__ out, int B)
{
    const int D = 64;
    const int gid = blockIdx.x * blockDim.x + threadIdx.x;
    const int sys = gid >> 4;   // 16 lanes per system
    const int g   = gid & 15;   // lane within group; holds elems [4g..4g+3]
    if (sys >= B) return;

    const int n_steps = *n_steps_p;
    const int se      = *store_every_p;
    const int n_chunks = n_steps / se;

    const float kt = *kT_p, m = *mass_p, q = *Q_p;
    const float c   = 0.25f * DT / q;     // alpha += c*(v2 - E)
    const float E   = (float)D * kt;
    const float hd  = 0.5f * DT / m;      // (DT/2)/mass
    const float hdt = 0.5f * DT;          // exp(-alpha*DT/2)

    const int snap4 = B * 16;             // float4s per snapshot (B*D/4)
    const int fidx  = sys * 16 + g;       // this lane's float4 slot

    const f4* x04 = (const f4*)x0;
    const f4* v04 = (const f4*)v0;
    f4 x = x04[fidx];
    f4 v = v04[fidx];
    float alpha = alpha0[sys];

    f4* outx = (f4*)out;                                    // traj_x
    f4* outv = ((f4*)out) + (size_t)(n_chunks + 1) * snap4; // traj_v

    // snapshot 0 = initial state
    __builtin_nontemporal_store(x, &outx[fidx]);
    __builtin_nontemporal_store(v, &outv[fidx]);

    float v2 = reduce16(v.x*v.x + v.y*v.y + v.z*v.z + v.w*v.w);

    for (int ck = 1; ck <= n_chunks; ++ck) {
        for (int s = 0; s < se; ++s) {
            // alpha update 1 (uses carried v2)
            alpha += c * (v2 - E);
            // first thermostat scaling
            float s1 = __expf(-hdt * alpha);
            v *= s1;
            v2 *= s1 * s1;
            // alpha update 2
            alpha += c * (v2 - E);
            // velocity-Verlet with force = -x
            v -= hd * x;
            x += DT * v;
            v -= hd * x;
            // the one real reduction per step
            float t = v.x*v.x;
            t = fmaf(v.y, v.y, t);
            t = fmaf(v.z, v.z, t);
            t = fmaf(v.w, v.w, t);
            v2 = reduce16(t);
            // alpha update 3
            alpha += c * (v2 - E);
            // second thermostat scaling
            float s2 = __expf(-hdt * alpha);
            v *= s2;
            v2 *= s2 * s2;
            // alpha update 4
            alpha += c * (v2 - E);
        }
        __builtin_nontemporal_store(x, &outx[(size_t)ck * snap4 + fidx]);
        __builtin_nontemporal_store(v, &outv[(size_t)ck * snap4 + fidx]);
    }
}

extern "C" void kernel_launch(void* const* d_in, const int* in_sizes, int n_in,
                              void* d_out, int out_size, void* d_ws, size_t ws_size,
                              hipStream_t stream) {
    const float* x0     = (const float*)d_in[0];
    const float* v0     = (const float*)d_in[1];
    const float* alpha0 = (const float*)d_in[2];
    const float* kT     = (const float*)d_in[3];
    const float* mass   = (const float*)d_in[4];
    const float* Q      = (const float*)d_in[5];
    const int* n_steps  = (const int*)d_in[6];
    const int* store_ev = (const int*)d_in[7];

    const int B = in_sizes[0] / 64;       // D = 64
    const int threads = B * 16;           // 16 lanes per system
    const int block = 256;
    const int grid = (threads + block - 1) / block;

    nh_kernel<<<grid, block, 0, stream>>>(x0, v0, alpha0, kT, mass, Q,
                                          n_steps, store_ev, (float*)d_out, B);
}

// Round 3
// 272.383 us; speedup vs baseline: 1.0882x; 1.0882x over previous
//
#include <hip/hip_runtime.h>

#define DT 0.001f

typedef float f4 __attribute__((ext_vector_type(4)));

// DPP row_ror ring all-reduce within each aligned group of 16 lanes.
template<int CTRL>
__device__ __forceinline__ float dpp_add(float v) {
    int r = __builtin_amdgcn_update_dpp(0, __float_as_int(v), CTRL, 0xf, 0xf, false);
    return v + __int_as_float(r);
}

__device__ __forceinline__ float reduce16(float t) {
    t = dpp_add<0x121>(t);  // row_ror:1
    t = dpp_add<0x122>(t);  // row_ror:2
    t = dpp_add<0x124>(t);  // row_ror:4
    t = dpp_add<0x128>(t);  // row_ror:8
    return t;
}

// exp(-z) for |z| <= ~0.01: degree-3 Taylor, error < 1e-9 rel.
__device__ __forceinline__ float expm(float z) {
    float p = __builtin_fmaf(z, -0.16666667f, 0.5f);
    p = __builtin_fmaf(z, p, -1.0f);
    p = __builtin_fmaf(z, p, 1.0f);
    return p;
}

__device__ __forceinline__ float sumsq(const f4& v) {
    float ta = v.x * v.x, tb = v.y * v.y, tc = v.z * v.z, td = v.w * v.w;
    return (ta + tb) + (tc + td);
}

// Steady-state chunk loop. SE>0: compile-time store_every (unrolled); SE==0: runtime.
template<int SE>
__device__ __forceinline__ void run(f4& x, f4& v, float& alpha, float& r,
                                    int n_chunks, int se_rt,
                                    float c, float cE, float c2E, float hd, float hdt,
                                    f4* outx, f4* outv, int snap4, int fidx)
{
    const int se = (SE > 0) ? SE : se_rt;
    const float c2 = 2.0f * c;
    for (int ck = 1; ck <= n_chunks; ++ck) {
        // A-half of the chunk's first step: U1, S1, U2
        alpha = __builtin_fmaf(c, r, alpha - cE);
        float s1 = expm(hdt * alpha);
        v *= s1;
        r *= s1 * s1;
        alpha = __builtin_fmaf(c, r, alpha - cE);
        // fused interior: completes step i's tail + step i+1's head
        #pragma unroll
        for (int i = 0; i < se - 1; ++i) {
            v -= hd * x;
            x += DT * v;
            v -= hd * x;
            r = reduce16(sumsq(v));
            alpha = __builtin_fmaf(c, r, alpha - cE);     // U3
            float s2 = expm(hdt * alpha);
            r *= s2 * s2;
            alpha = __builtin_fmaf(c2, r, alpha - c2E);   // U4 + U1 (v unchanged between)
            float s1n = expm(hdt * alpha);
            v *= s2 * s1n;                                // S2 then S1, fused
            r *= s1n * s1n;
            alpha = __builtin_fmaf(c, r, alpha - cE);     // U2
        }
        // final step of chunk: Verlet, R, U3, S2, U4 (clean boundary for snapshot)
        v -= hd * x;
        x += DT * v;
        v -= hd * x;
        r = reduce16(sumsq(v));
        alpha = __builtin_fmaf(c, r, alpha - cE);         // U3
        float s2 = expm(hdt * alpha);
        v *= s2;
        r *= s2 * s2;
        alpha = __builtin_fmaf(c, r, alpha - cE);         // U4
        __builtin_nontemporal_store(x, &outx[(size_t)ck * snap4 + fidx]);
        __builtin_nontemporal_store(v, &outv[(size_t)ck * snap4 + fidx]);
    }
}

__global__ __launch_bounds__(256) void nh_kernel(
    const float* __restrict__ x0, const float* __restrict__ v0,
    const float* __restrict__ alpha0,
    const float* __restrict__ kT_p, const float* __restrict__ mass_p,
    const float* __restrict__ Q_p,
    const int* __restrict__ n_steps_p, const int* __restrict__ store_every_p,
    float* __restrict__ out, int B)
{
    const int D = 64;
    const int gid = blockIdx.x * blockDim.x + threadIdx.x;
    const int sys = gid >> 4;   // 16 lanes per system
    const int g   = gid & 15;   // lane holds elems [4g..4g+3]
    if (sys >= B) return;

    const int n_steps = *n_steps_p;
    const int se      = *store_every_p;
    const int n_chunks = n_steps / se;

    const float kt = *kT_p, m = *mass_p, q = *Q_p;
    const float c   = 0.25f * DT / q;
    const float E   = (float)D * kt;
    const float cE  = c * E;
    const float c2E = 2.0f * cE;
    const float hd  = 0.5f * DT / m;
    const float hdt = 0.5f * DT;

    const int snap4 = B * 16;
    const int fidx  = sys * 16 + g;

    f4 x = ((const f4*)x0)[fidx];
    f4 v = ((const f4*)v0)[fidx];
    float alpha = alpha0[sys];

    f4* outx = (f4*)out;
    f4* outv = ((f4*)out) + (size_t)(n_chunks + 1) * snap4;

    // snapshot 0
    __builtin_nontemporal_store(x, &outx[fidx]);
    __builtin_nontemporal_store(v, &outv[fidx]);

    float r = reduce16(sumsq(v));

    if (se == 10)
        run<10>(x, v, alpha, r, n_chunks, se, c, cE, c2E, hd, hdt, outx, outv, snap4, fidx);
    else
        run<0>(x, v, alpha, r, n_chunks, se, c, cE, c2E, hd, hdt, outx, outv, snap4, fidx);
}

extern "C" void kernel_launch(void* const* d_in, const int* in_sizes, int n_in,
                              void* d_out, int out_size, void* d_ws, size_t ws_size,
                              hipStream_t stream) {
    const float* x0     = (const float*)d_in[0];
    const float* v0     = (const float*)d_in[1];
    const float* alpha0 = (const float*)d_in[2];
    const float* kT     = (const float*)d_in[3];
    const float* mass   = (const float*)d_in[4];
    const float* Q      = (const float*)d_in[5];
    const int* n_steps  = (const int*)d_in[6];
    const int* store_ev = (const int*)d_in[7];

    const int B = in_sizes[0] / 64;       // D = 64
    const int threads = B * 16;
    const int block = 256;
    const int grid = (threads + block - 1) / block;

    nh_kernel<<<grid, block, 0, stream>>>(x0, v0, alpha0, kT, mass, Q,
                                          n_steps, store_ev, (float*)d_out, B);
}